// Round 7
// baseline (213.265 us; speedup 1.0000x reference)
//
#include <hip/hip_runtime.h>

#define NS 7
#define NK 6
#define TW 294   // torsion row width = NS*NS*NK
#define TPB 32   // triplets per block

typedef float f4 __attribute__((ext_vector_type(4)));

// spherical Bessel j_n via upward recurrence (matches numpy/jnp closed form)
__device__ __forceinline__ float jl_runtime(float x, int n) {
    float s, c;
    sincosf(x, &s, &c);
    float inv = 1.0f / x;
    float j0 = s * inv;
    if (n == 0) return j0;
    float jm = j0;
    float j = (s * inv - c) * inv;
    for (int l = 2; l <= n; ++l) {
        float t = (float)(2 * l - 1) * inv * j - jm;
        jm = j;
        j = t;
    }
    return j;
}

// j_{l-1} and j_l together (for Newton)
__device__ __forceinline__ void jl_pair(float x, int l, float* jlm1, float* jl) {
    float s, c;
    sincosf(x, &s, &c);
    float inv = 1.0f / x;
    float jm = c * inv;        // j_{-1}
    float j = s * inv;         // j_0
    for (int ll = 1; ll <= l; ++ll) {
        float t = (float)(2 * ll - 1) * inv * j - jm;
        jm = j;
        j = t;
    }
    *jlm1 = jm;
    *jl = j;
}

// Fused: dist embedding for all blocks; LAST block additionally computes the
// constant tables into ws. ws layout (floats):
// [0..41] z[l*6+i], [42..83] norm[l*6+i], [84..132] K[49 flat sph-harm]
__global__ void dist_init_kernel(const float* __restrict__ dist,
                                 const float* __restrict__ freq,
                                 float* __restrict__ out, int E,
                                 float* __restrict__ ws) {
    __shared__ __align__(16) float buf[256 * 6];
    const int tid = threadIdx.x;
    const int e0 = blockIdx.x * 256;
    int e = e0 + tid;
    int ec = e < E ? e : E - 1;
    float x = dist[ec] * 0.2f;
    float inv = 1.0f / x;
    float x2 = x * x;
    float xp0 = x2 * x2 * x;  // x^5
    float env = inv - 28.0f * xp0 + 48.0f * xp0 * x - 21.0f * xp0 * x2;
    float v[NK];
    #pragma unroll
    for (int i = 0; i < NK; ++i) v[i] = env * sinf(freq[i] * x);
    if (e0 + 256 <= E) {
        #pragma unroll
        for (int i = 0; i < NK; ++i) buf[tid * 6 + i] = v[i];
        __syncthreads();
        const f4* b4 = (const f4*)buf;
        f4* o4 = (f4*)(out + (size_t)e0 * 6);
        o4[tid] = b4[tid];
        if (tid < 128) o4[256 + tid] = b4[256 + tid];
    } else if (e < E) {
        #pragma unroll
        for (int i = 0; i < NK; ++i) out[(size_t)e * 6 + i] = v[i];
    }

    if (blockIdx.x == gridDim.x - 1) {
        // ---- init constants (all 256 threads traverse the same syncs, work masked)
        __shared__ float zsh[NS][NK + NS - 1];
        const int total = NK + NS - 1;  // 12
        if (tid < total) zsh[0][tid] = (float)((tid + 1) * 3.14159265358979323846);
        __syncthreads();
        for (int l = 1; l < NS; ++l) {
            if (tid < total - l) {
                float a = zsh[l - 1][tid], b = zsh[l - 1][tid + 1];
                float fa = jl_runtime(a, l);
                for (int it = 0; it < 12; ++it) {   // bracket to ~1e-3
                    float m = 0.5f * (a + b);
                    float fm = jl_runtime(m, l);
                    if (fa * fm <= 0.0f) { b = m; }
                    else { a = m; fa = fm; }
                }
                float xx = 0.5f * (a + b);
                #pragma unroll
                for (int it = 0; it < 3; ++it) {    // Newton polish
                    float jm1, jv;
                    jl_pair(xx, l, &jm1, &jv);
                    float d = jm1 - (float)(l + 1) / xx * jv;  // j_l'(x)
                    xx -= jv / d;
                }
                zsh[l][tid] = xx;
            }
            __syncthreads();
        }
        if (tid < 42) {
            int l = tid / 6, i = tid % 6;
            float z = zsh[l][i];
            float jn1 = jl_runtime(z, l + 1);
            ws[tid] = z;
            ws[42 + tid] = 1.0f / sqrtf(0.5f * jn1 * jn1);
        }
        if (tid < 49) {
            int f = tid;
            int l = 0;
            while ((l + 1) * (l + 1) <= f) ++l;
            int m = f - l * l - l;
            int am = m < 0 ? -m : m;
            float ratio = 1.0f;
            for (int t = l - am + 1; t <= l + am; ++t) ratio /= (float)t;
            float K = sqrtf((float)(2 * l + 1) * 0.07957747154594767f * ratio);
            if (m != 0) K *= 1.41421356237309505f;
            ws[84 + f] = K;
        }
    }
}

__launch_bounds__(256, 8)
__global__ void triplet_kernel(const float* __restrict__ dist,
                               const float* __restrict__ angle,
                               const float* __restrict__ torsion,
                               const int* __restrict__ idx_kj,
                               const float* __restrict__ consts,
                               float* __restrict__ outA,
                               float* __restrict__ outT,
                               int T) {
    __shared__ __align__(16) float rbf_s[TPB][44];  // even stride: b64 reads stay 8B-aligned
    __shared__ float cbf_s[TPB][49];                // odd stride: good bank spread
    const int tid = threadIdx.x;
    const int t0 = blockIdx.x * TPB;
    const float* __restrict__ Kg = consts + 84;

    if (tid < TPB) {
        // ---- cbf[49] for triplet slot `tid`, m-major (3-deep P chain)
        int t = t0 + tid;
        int tc = t < T ? t : T - 1;
        float ang = angle[tc];
        float phi = torsion[tc];

        float ct, st;
        sincosf(ang, &st, &ct);
        float sp, cp;
        sincosf(phi, &sp, &cp);
        float sm[NS], cm[NS];
        sm[1] = sp; cm[1] = cp;
        #pragma unroll
        for (int m = 2; m < NS; ++m) {
            sm[m] = sm[m - 1] * cp + cm[m - 1] * sp;
            cm[m] = cm[m - 1] * cp - sm[m - 1] * sp;
        }

        float* cb = cbf_s[tid];
        float pmm = 1.0f;  // P[m][m]
        #pragma unroll
        for (int m = 0; m < NS; ++m) {
            if (m > 0) pmm = (float)(1 - 2 * m) * pmm * st;
            {
                int f = m * m + m;
                if (m == 0) cb[f] = Kg[f];
                else {
                    cb[f + m] = Kg[f + m] * cm[m] * pmm;
                    cb[f - m] = Kg[f - m] * sm[m] * pmm;
                }
            }
            if (m < NS - 1) {
                float plm1 = pmm;
                float pl = (float)(2 * m + 1) * ct * pmm;  // P[m+1][m]
                {
                    int l = m + 1, f = l * l + l;
                    if (m == 0) cb[f] = Kg[f] * pl;
                    else {
                        cb[f + m] = Kg[f + m] * cm[m] * pl;
                        cb[f - m] = Kg[f - m] * sm[m] * pl;
                    }
                }
                #pragma unroll
                for (int l = m + 2; l < NS; ++l) {
                    float pn = ((float)(2 * l - 1) * ct * pl -
                                (float)(l + m - 1) * plm1) / (float)(l - m);
                    plm1 = pl; pl = pn;
                    int f = l * l + l;
                    if (m == 0) cb[f] = Kg[f] * pl;
                    else {
                        cb[f + m] = Kg[f + m] * cm[m] * pl;
                        cb[f - m] = Kg[f - m] * sm[m] * pl;
                    }
                }
            }
        }
    } else if (tid >= 64 && tid < 64 + 6 * TPB) {
        // ---- rbf: 6 threads per triplet, 7 Bessel evals each
        int w = tid - 64;
        int s = w / 6, p = w - 6 * s;
        int t = t0 + s;
        int tc = t < T ? t : T - 1;
        int idx = idx_kj[tc];
        float x = dist[idx] * 0.2f;
        int jlo = p * 7;
        for (int jj = jlo; jj < jlo + 7; ++jj) {
            int l = jj / 6;
            float arg = consts[jj] * x;
            float s1, c1;
            sincosf(arg, &s1, &c1);
            float inv = 1.0f / arg;
            float j0 = s1 * inv;
            float val = j0;
            if (l >= 1) {
                float jm = j0;
                float jcur = (s1 * inv - c1) * inv;
                for (int ll = 2; ll <= l; ++ll) {
                    float tmp = (float)(2 * ll - 1) * inv * jcur - jm;
                    jm = jcur;
                    jcur = tmp;
                }
                val = jcur;
            }
            rbf_s[s][jj] = consts[42 + jj] * val;
        }
    }
    __syncthreads();

    int nvalid = T - t0; if (nvalid > TPB) nvalid = TPB;

    if (nvalid == TPB) {
        // ---- phase 2: direct register products -> flat plain dwordx4 stores.
        // Torsion block region = 32*294 floats = 2352 x 16B chunks.
        // Even col-pair shares a = c/42 and q = a*7 + (c%42)/6 (q never splits a pair).
        f4* __restrict__ gT = (f4*)(outT + (size_t)t0 * TW);
        unsigned row = (unsigned)(4 * tid) / 294u;
        unsigned c   = (unsigned)(4 * tid) - row * 294u;
        #pragma unroll
        for (int it = 0; it < 10; ++it) {
            if (it < 9 || tid < 48) {
                unsigned row1 = row, c1 = c + 2;
                if (c1 >= 294u) { c1 -= 294u; row1 += 1; }
                unsigned a0 = c / 42u,  r0 = c - a0 * 42u,  q0 = a0 * 7u + r0 / 6u;
                unsigned a1 = c1 / 42u, r1 = c1 - a1 * 42u, q1 = a1 * 7u + r1 / 6u;
                float qv0 = cbf_s[row][q0];
                float2 rv0 = *(const float2*)&rbf_s[row][r0];
                float qv1 = cbf_s[row1][q1];
                float2 rv1 = *(const float2*)&rbf_s[row1][r1];
                f4 val = { qv0 * rv0.x, qv0 * rv0.y, qv1 * rv1.x, qv1 * rv1.y };
                gT[it * 256 + tid] = val;
            }
            c += 142u; row += 3u;
            if (c >= 294u) { c -= 294u; row += 1u; }
        }
        // Angle block region = 32*42 floats = 336 x 16B chunks.
        f4* __restrict__ gA = (f4*)(outA + (size_t)t0 * 42);
        unsigned arow = (unsigned)(4 * tid) / 42u;
        unsigned ac   = (unsigned)(4 * tid) - arow * 42u;
        #pragma unroll
        for (int it = 0; it < 2; ++it) {
            if (it < 1 || tid < 80) {
                unsigned arow1 = arow, ac1 = ac + 2;
                if (ac1 >= 42u) { ac1 -= 42u; arow1 += 1; }
                unsigned l0 = ac / 6u,  qa0 = l0 * l0 + l0;
                unsigned l1 = ac1 / 6u, qa1 = l1 * l1 + l1;
                float qv0 = cbf_s[arow][qa0];
                float2 rv0 = *(const float2*)&rbf_s[arow][ac];
                float qv1 = cbf_s[arow1][qa1];
                float2 rv1 = *(const float2*)&rbf_s[arow1][ac1];
                f4 val = { qv0 * rv0.x, qv0 * rv0.y, qv1 * rv1.x, qv1 * rv1.y };
                gA[it * 256 + tid] = val;
            }
            ac += 16u; arow += 24u;  // +1024 floats = 24*42 + 16
            if (ac >= 42u) { ac -= 42u; arow += 1u; }
        }
    } else {
        // partial tail block (not hit when T % TPB == 0) — safe scalar path
        for (int g = tid; g < nvalid * TW; g += 256) {
            int row = g / TW, cc = g - row * TW;
            int a = cc / 42, r = cc - a * 42;
            outT[(size_t)t0 * TW + g] = cbf_s[row][a * 7 + r / 6] * rbf_s[row][r];
        }
        for (int g = tid; g < nvalid * 42; g += 256) {
            int row = g / 42, r = g - row * 42;
            int l = r / 6;
            outA[(size_t)t0 * 42 + g] = cbf_s[row][l * l + l] * rbf_s[row][r];
        }
    }
}

extern "C" void kernel_launch(void* const* d_in, const int* in_sizes, int n_in,
                              void* d_out, int out_size, void* d_ws, size_t ws_size,
                              hipStream_t stream) {
    const float* dist    = (const float*)d_in[0];
    const float* angle   = (const float*)d_in[1];
    const float* torsion = (const float*)d_in[2];
    const float* freq    = (const float*)d_in[3];
    const int*   idx_kj  = (const int*)d_in[4];
    const int E = in_sizes[0];
    const int T = in_sizes[1];
    float* out = (float*)d_out;
    float* consts = (float*)d_ws;

    dist_init_kernel<<<(E + 255) / 256, 256, 0, stream>>>(dist, freq, out, E, consts);
    float* outA = out + (size_t)E * NK;
    float* outT = outA + (size_t)T * 42;
    triplet_kernel<<<(T + TPB - 1) / TPB, 256, 0, stream>>>(dist, angle, torsion, idx_kj,
                                                            consts, outA, outT, T);
}

// Round 8
// 184.704 us; speedup vs baseline: 1.1546x; 1.1546x over previous
//
#include <hip/hip_runtime.h>

#define NS 7
#define NK 6
#define TW 294   // torsion row width = NS*NS*NK
#define TPB 32   // triplets per block

typedef float f4 __attribute__((ext_vector_type(4)));

// spherical Bessel j_n via upward recurrence (matches numpy/jnp closed form)
__device__ __forceinline__ float jl_runtime(float x, int n) {
    float s, c;
    sincosf(x, &s, &c);
    float inv = 1.0f / x;
    float j0 = s * inv;
    if (n == 0) return j0;
    float jm = j0;
    float j = (s * inv - c) * inv;
    for (int l = 2; l <= n; ++l) {
        float t = (float)(2 * l - 1) * inv * j - jm;
        jm = j;
        j = t;
    }
    return j;
}

// j_{l-1} and j_l together (for Newton)
__device__ __forceinline__ void jl_pair(float x, int l, float* jlm1, float* jl) {
    float s, c;
    sincosf(x, &s, &c);
    float inv = 1.0f / x;
    float jm = c * inv;        // j_{-1}
    float j = s * inv;         // j_0
    for (int ll = 1; ll <= l; ++ll) {
        float t = (float)(2 * ll - 1) * inv * j - jm;
        jm = j;
        j = t;
    }
    *jlm1 = jm;
    *jl = j;
}

// Fused: dist embedding for all blocks; LAST block additionally computes the
// constant tables into ws. ws layout (floats):
// [0..41] z[l*6+i], [42..83] norm[l*6+i], [84..132] K[49 flat sph-harm]
__global__ void dist_init_kernel(const float* __restrict__ dist,
                                 const float* __restrict__ freq,
                                 float* __restrict__ out, int E,
                                 float* __restrict__ ws) {
    __shared__ __align__(16) float buf[256 * 6];
    const int tid = threadIdx.x;
    const int e0 = blockIdx.x * 256;
    int e = e0 + tid;
    int ec = e < E ? e : E - 1;
    float x = dist[ec] * 0.2f;
    float inv = 1.0f / x;
    float x2 = x * x;
    float xp0 = x2 * x2 * x;  // x^5
    float env = inv - 28.0f * xp0 + 48.0f * xp0 * x - 21.0f * xp0 * x2;
    float v[NK];
    #pragma unroll
    for (int i = 0; i < NK; ++i) v[i] = env * sinf(freq[i] * x);
    if (e0 + 256 <= E) {
        #pragma unroll
        for (int i = 0; i < NK; ++i) buf[tid * 6 + i] = v[i];
        __syncthreads();
        const f4* b4 = (const f4*)buf;
        f4* o4 = (f4*)(out + (size_t)e0 * 6);
        __builtin_nontemporal_store(b4[tid], o4 + tid);
        if (tid < 128) __builtin_nontemporal_store(b4[256 + tid], o4 + 256 + tid);
    } else if (e < E) {
        #pragma unroll
        for (int i = 0; i < NK; ++i) out[(size_t)e * 6 + i] = v[i];
    }

    if (blockIdx.x == gridDim.x - 1) {
        // ---- init constants (all 256 threads traverse the same syncs, work masked)
        __shared__ float zsh[NS][NK + NS - 1];
        const int total = NK + NS - 1;  // 12
        if (tid < total) zsh[0][tid] = (float)((tid + 1) * 3.14159265358979323846);
        __syncthreads();
        for (int l = 1; l < NS; ++l) {
            if (tid < total - l) {
                float a = zsh[l - 1][tid], b = zsh[l - 1][tid + 1];
                float fa = jl_runtime(a, l);
                for (int it = 0; it < 12; ++it) {   // bracket to ~1e-3
                    float m = 0.5f * (a + b);
                    float fm = jl_runtime(m, l);
                    if (fa * fm <= 0.0f) { b = m; }
                    else { a = m; fa = fm; }
                }
                float xx = 0.5f * (a + b);
                #pragma unroll
                for (int it = 0; it < 3; ++it) {    // Newton polish
                    float jm1, jv;
                    jl_pair(xx, l, &jm1, &jv);
                    float d = jm1 - (float)(l + 1) / xx * jv;  // j_l'(x)
                    xx -= jv / d;
                }
                zsh[l][tid] = xx;
            }
            __syncthreads();
        }
        if (tid < 42) {
            int l = tid / 6, i = tid % 6;
            float z = zsh[l][i];
            float jn1 = jl_runtime(z, l + 1);
            ws[tid] = z;
            ws[42 + tid] = 1.0f / sqrtf(0.5f * jn1 * jn1);
        }
        if (tid < 49) {
            int f = tid;
            int l = 0;
            while ((l + 1) * (l + 1) <= f) ++l;
            int m = f - l * l - l;
            int am = m < 0 ? -m : m;
            float ratio = 1.0f;
            for (int t = l - am + 1; t <= l + am; ++t) ratio /= (float)t;
            float K = sqrtf((float)(2 * l + 1) * 0.07957747154594767f * ratio);
            if (m != 0) K *= 1.41421356237309505f;
            ws[84 + f] = K;
        }
    }
}

__launch_bounds__(256, 8)
__global__ void triplet_kernel(const float* __restrict__ dist,
                               const float* __restrict__ angle,
                               const float* __restrict__ torsion,
                               const int* __restrict__ idx_kj,
                               const float* __restrict__ consts,
                               float* __restrict__ outA,
                               float* __restrict__ outT,
                               int T) {
    __shared__ __align__(16) float rbf_s[TPB][44];  // even stride: b64 reads stay 8B-aligned
    __shared__ float cbf_s[TPB][49];                // odd stride: good bank spread
    const int tid = threadIdx.x;
    const int t0 = blockIdx.x * TPB;
    const float* __restrict__ Kg = consts + 84;

    if (tid < TPB) {
        // ---- cbf[49] for triplet slot `tid`, m-major (3-deep P chain)
        int t = t0 + tid;
        int tc = t < T ? t : T - 1;
        float ang = angle[tc];
        float phi = torsion[tc];

        float ct, st;
        sincosf(ang, &st, &ct);
        float sp, cp;
        sincosf(phi, &sp, &cp);
        float sm[NS], cm[NS];
        sm[1] = sp; cm[1] = cp;
        #pragma unroll
        for (int m = 2; m < NS; ++m) {
            sm[m] = sm[m - 1] * cp + cm[m - 1] * sp;
            cm[m] = cm[m - 1] * cp - sm[m - 1] * sp;
        }

        float* cb = cbf_s[tid];
        float pmm = 1.0f;  // P[m][m]
        #pragma unroll
        for (int m = 0; m < NS; ++m) {
            if (m > 0) pmm = (float)(1 - 2 * m) * pmm * st;
            {
                int f = m * m + m;
                if (m == 0) cb[f] = Kg[f];
                else {
                    cb[f + m] = Kg[f + m] * cm[m] * pmm;
                    cb[f - m] = Kg[f - m] * sm[m] * pmm;
                }
            }
            if (m < NS - 1) {
                float plm1 = pmm;
                float pl = (float)(2 * m + 1) * ct * pmm;  // P[m+1][m]
                {
                    int l = m + 1, f = l * l + l;
                    if (m == 0) cb[f] = Kg[f] * pl;
                    else {
                        cb[f + m] = Kg[f + m] * cm[m] * pl;
                        cb[f - m] = Kg[f - m] * sm[m] * pl;
                    }
                }
                #pragma unroll
                for (int l = m + 2; l < NS; ++l) {
                    float pn = ((float)(2 * l - 1) * ct * pl -
                                (float)(l + m - 1) * plm1) / (float)(l - m);
                    plm1 = pl; pl = pn;
                    int f = l * l + l;
                    if (m == 0) cb[f] = Kg[f] * pl;
                    else {
                        cb[f + m] = Kg[f + m] * cm[m] * pl;
                        cb[f - m] = Kg[f - m] * sm[m] * pl;
                    }
                }
            }
        }
    } else if (tid >= 64 && tid < 64 + 6 * TPB) {
        // ---- rbf: 6 threads per triplet, 7 Bessel evals each
        int w = tid - 64;
        int s = w / 6, p = w - 6 * s;
        int t = t0 + s;
        int tc = t < T ? t : T - 1;
        int idx = idx_kj[tc];
        float x = dist[idx] * 0.2f;
        int jlo = p * 7;
        for (int jj = jlo; jj < jlo + 7; ++jj) {
            int l = jj / 6;
            float arg = consts[jj] * x;
            float s1, c1;
            sincosf(arg, &s1, &c1);
            float inv = 1.0f / arg;
            float j0 = s1 * inv;
            float val = j0;
            if (l >= 1) {
                float jm = j0;
                float jcur = (s1 * inv - c1) * inv;
                for (int ll = 2; ll <= l; ++ll) {
                    float tmp = (float)(2 * ll - 1) * inv * jcur - jm;
                    jm = jcur;
                    jcur = tmp;
                }
                val = jcur;
            }
            rbf_s[s][jj] = consts[42 + jj] * val;
        }
    }
    __syncthreads();

    int nvalid = T - t0; if (nvalid > TPB) nvalid = TPB;

    if (nvalid == TPB) {
        // ---- phase 2: direct register products -> flat nontemporal dwordx4 stores.
        // Torsion block region = 32*294 floats = 2352 x 16B chunks.
        // Even col-pair shares a = c/42 and q = a*7 + (c%42)/6 (q never splits a pair).
        f4* __restrict__ gT = (f4*)(outT + (size_t)t0 * TW);
        unsigned row = (unsigned)(4 * tid) / 294u;
        unsigned c   = (unsigned)(4 * tid) - row * 294u;
        #pragma unroll
        for (int it = 0; it < 10; ++it) {
            if (it < 9 || tid < 48) {
                unsigned row1 = row, c1 = c + 2;
                if (c1 >= 294u) { c1 -= 294u; row1 += 1; }
                unsigned a0 = c / 42u,  r0 = c - a0 * 42u,  q0 = a0 * 7u + r0 / 6u;
                unsigned a1 = c1 / 42u, r1 = c1 - a1 * 42u, q1 = a1 * 7u + r1 / 6u;
                float qv0 = cbf_s[row][q0];
                float2 rv0 = *(const float2*)&rbf_s[row][r0];
                float qv1 = cbf_s[row1][q1];
                float2 rv1 = *(const float2*)&rbf_s[row1][r1];
                f4 val = { qv0 * rv0.x, qv0 * rv0.y, qv1 * rv1.x, qv1 * rv1.y };
                __builtin_nontemporal_store(val, gT + it * 256 + tid);
            }
            c += 142u; row += 3u;
            if (c >= 294u) { c -= 294u; row += 1u; }
        }
        // Angle block region = 32*42 floats = 336 x 16B chunks.
        f4* __restrict__ gA = (f4*)(outA + (size_t)t0 * 42);
        unsigned arow = (unsigned)(4 * tid) / 42u;
        unsigned ac   = (unsigned)(4 * tid) - arow * 42u;
        #pragma unroll
        for (int it = 0; it < 2; ++it) {
            if (it < 1 || tid < 80) {
                unsigned arow1 = arow, ac1 = ac + 2;
                if (ac1 >= 42u) { ac1 -= 42u; arow1 += 1; }
                unsigned l0 = ac / 6u,  qa0 = l0 * l0 + l0;
                unsigned l1 = ac1 / 6u, qa1 = l1 * l1 + l1;
                float qv0 = cbf_s[arow][qa0];
                float2 rv0 = *(const float2*)&rbf_s[arow][ac];
                float qv1 = cbf_s[arow1][qa1];
                float2 rv1 = *(const float2*)&rbf_s[arow1][ac1];
                f4 val = { qv0 * rv0.x, qv0 * rv0.y, qv1 * rv1.x, qv1 * rv1.y };
                __builtin_nontemporal_store(val, gA + it * 256 + tid);
            }
            ac += 16u; arow += 24u;  // +1024 floats = 24*42 + 16
            if (ac >= 42u) { ac -= 42u; arow += 1u; }
        }
    } else {
        // partial tail block (not hit when T % TPB == 0) — safe scalar path
        for (int g = tid; g < nvalid * TW; g += 256) {
            int row = g / TW, cc = g - row * TW;
            int a = cc / 42, r = cc - a * 42;
            outT[(size_t)t0 * TW + g] = cbf_s[row][a * 7 + r / 6] * rbf_s[row][r];
        }
        for (int g = tid; g < nvalid * 42; g += 256) {
            int row = g / 42, r = g - row * 42;
            int l = r / 6;
            outA[(size_t)t0 * 42 + g] = cbf_s[row][l * l + l] * rbf_s[row][r];
        }
    }
}

extern "C" void kernel_launch(void* const* d_in, const int* in_sizes, int n_in,
                              void* d_out, int out_size, void* d_ws, size_t ws_size,
                              hipStream_t stream) {
    const float* dist    = (const float*)d_in[0];
    const float* angle   = (const float*)d_in[1];
    const float* torsion = (const float*)d_in[2];
    const float* freq    = (const float*)d_in[3];
    const int*   idx_kj  = (const int*)d_in[4];
    const int E = in_sizes[0];
    const int T = in_sizes[1];
    float* out = (float*)d_out;
    float* consts = (float*)d_ws;

    dist_init_kernel<<<(E + 255) / 256, 256, 0, stream>>>(dist, freq, out, E, consts);
    float* outA = out + (size_t)E * NK;
    float* outT = outA + (size_t)T * 42;
    triplet_kernel<<<(T + TPB - 1) / TPB, 256, 0, stream>>>(dist, angle, torsion, idx_kj,
                                                            consts, outA, outT, T);
}

// Round 9
// 160.300 us; speedup vs baseline: 1.3304x; 1.1522x over previous
//
#include <hip/hip_runtime.h>

#define NS 7
#define NK 6
#define TW 294   // torsion row width = NS*NS*NK
#define TPB 32   // triplets per block

typedef float f4 __attribute__((ext_vector_type(4)));

// Initial guesses for zeros of spherical Bessel j_l, l=1..6, k=1..6.
// Polished on-device by 4 Newton iterations (quadratic convergence; spacing
// between zeros ~pi so guesses accurate to ~1e-3 converge to f32 machine eps).
__constant__ float ZG[6][6] = {
    {4.4934095f, 7.7252518f, 10.9041217f, 14.0661939f, 17.2207553f, 20.3713030f},
    {5.7634592f, 9.0950113f, 12.3229410f, 15.5146030f, 18.6890364f, 21.8538742f},
    {6.9879320f, 10.4171185f, 13.6980232f, 16.9236213f, 20.1218062f, 23.3042470f},
    {8.1825615f, 11.7049072f, 15.0396647f, 18.3012560f, 21.5254177f, 24.7275655f},
    {9.3558121f, 12.9665302f, 16.3547096f, 19.6531521f, 22.9045506f, 26.1277501f},
    {10.5128354f, 14.2073925f, 17.6479743f, 20.9834631f, 24.2627681f, 27.5078684f}
};

// j_{l-1}, j_l at x via upward recurrence; pure-value sinf/cosf (no sincos
// out-pointer -> no risk of scratch round-trip).
__device__ __forceinline__ void jl_pair(float x, int l, float* jlm1, float* jl) {
    float s = sinf(x), c = cosf(x);
    float inv = 1.0f / x;
    float jm = c * inv;        // j_{-1}
    float j = s * inv;         // j_0
    for (int ll = 1; ll <= l; ++ll) {
        float t = (float)(2 * ll - 1) * inv * j - jm;
        jm = j;
        j = t;
    }
    *jlm1 = jm;
    *jl = j;
}

__launch_bounds__(256, 8)
__global__ void fused_kernel(const float* __restrict__ dist,
                             const float* __restrict__ angle,
                             const float* __restrict__ torsion,
                             const float* __restrict__ freq,
                             const int* __restrict__ idx_kj,
                             float* __restrict__ outD,
                             float* __restrict__ outA,
                             float* __restrict__ outT,
                             int E, int T, int NBT) {
    // shared memory union:
    // triplet path: rbf [32][44] @0, cbf [32][49] @1408, zc @2976, nc @3018, Kc @3060
    // dist path:    buf[1536] @0
    __shared__ __align__(16) float smem[3112];
    const int tid = threadIdx.x;

    if (blockIdx.x >= NBT) {
        // ================= dist-embedding path =================
        const int e0 = (blockIdx.x - NBT) * 256;
        int e = e0 + tid;
        int ec = e < E ? e : E - 1;
        float x = dist[ec] * 0.2f;
        float inv = 1.0f / x;
        float x2 = x * x;
        float xp0 = x2 * x2 * x;  // x^5
        float env = inv - 28.0f * xp0 + 48.0f * xp0 * x - 21.0f * xp0 * x2;
        float v[NK];
        #pragma unroll
        for (int i = 0; i < NK; ++i) v[i] = env * sinf(freq[i] * x);
        if (e0 + 256 <= E) {
            #pragma unroll
            for (int i = 0; i < NK; ++i) smem[tid * 6 + i] = v[i];
            __syncthreads();
            const f4* b4 = (const f4*)smem;
            f4* o4 = (f4*)(outD + (size_t)e0 * 6);
            __builtin_nontemporal_store(b4[tid], o4 + tid);
            if (tid < 128) __builtin_nontemporal_store(b4[256 + tid], o4 + 256 + tid);
        } else if (e < E) {
            #pragma unroll
            for (int i = 0; i < NK; ++i) outD[(size_t)e * 6 + i] = v[i];
        }
        return;
    }

    // ================= triplet path =================
    float* __restrict__ rbf_s = smem;          // [32][44]
    float* __restrict__ cbf_s = smem + 1408;   // [32][49]
    float* __restrict__ zc    = smem + 2976;   // 42
    float* __restrict__ nc    = smem + 3018;   // 42
    float* __restrict__ Kc    = smem + 3060;   // 49

    // ---- phase 0: per-block constant tables (cheap; hidden under store backpressure)
    if (tid < 42) {
        int l = tid / 6, i = tid - 6 * l;
        if (l == 0) {
            float z = (float)(i + 1) * 3.14159265358979f;
            zc[tid] = z;
            nc[tid] = z * 1.41421356237309f;   // sqrt(2)*k*pi exactly
        } else {
            float x = ZG[l - 1][i];
            #pragma unroll
            for (int it = 0; it < 4; ++it) {   // Newton polish
                float jm, jv;
                jl_pair(x, l, &jm, &jv);
                float d = jm - (float)(l + 1) / x * jv;  // j_l'(x)
                x -= jv / d;
            }
            float jm, jv;
            jl_pair(x, l, &jm, &jv);
            float jn1 = (float)(2 * l + 1) / x * jv - jm;  // j_{l+1}(x)
            zc[tid] = x;
            nc[tid] = 1.41421356237309f / fabsf(jn1);
        }
    } else if (tid >= 64 && tid < 113) {
        int f = tid - 64;
        int l = 0;
        while ((l + 1) * (l + 1) <= f) ++l;
        int m = f - l * l - l;
        int am = m < 0 ? -m : m;
        float ratio = 1.0f;
        for (int t = l - am + 1; t <= l + am; ++t) ratio /= (float)t;
        float K = sqrtf((float)(2 * l + 1) * 0.07957747154594767f * ratio);
        if (m != 0) K *= 1.41421356237309505f;
        Kc[f] = K;
    }
    const int t0 = blockIdx.x * TPB;
    __syncthreads();

    // ---- phase 1
    if (tid < TPB) {
        // cbf[49] for triplet slot `tid`, m-major (3-deep P chain)
        int t = t0 + tid;
        int tc = t < T ? t : T - 1;
        float ang = angle[tc];
        float phi = torsion[tc];

        float st = sinf(ang), ct = cosf(ang);
        float sp = sinf(phi), cp = cosf(phi);
        float sm[NS], cm[NS];
        sm[1] = sp; cm[1] = cp;
        #pragma unroll
        for (int m = 2; m < NS; ++m) {
            sm[m] = sm[m - 1] * cp + cm[m - 1] * sp;
            cm[m] = cm[m - 1] * cp - sm[m - 1] * sp;
        }

        float* cb = cbf_s + tid * 49;
        float pmm = 1.0f;  // P[m][m]
        #pragma unroll
        for (int m = 0; m < NS; ++m) {
            if (m > 0) pmm = (float)(1 - 2 * m) * pmm * st;
            {
                int f = m * m + m;
                if (m == 0) cb[f] = Kc[f];
                else {
                    cb[f + m] = Kc[f + m] * cm[m] * pmm;
                    cb[f - m] = Kc[f - m] * sm[m] * pmm;
                }
            }
            if (m < NS - 1) {
                float plm1 = pmm;
                float pl = (float)(2 * m + 1) * ct * pmm;  // P[m+1][m]
                {
                    int l = m + 1, f = l * l + l;
                    if (m == 0) cb[f] = Kc[f] * pl;
                    else {
                        cb[f + m] = Kc[f + m] * cm[m] * pl;
                        cb[f - m] = Kc[f - m] * sm[m] * pl;
                    }
                }
                #pragma unroll
                for (int l = m + 2; l < NS; ++l) {
                    float pn = ((float)(2 * l - 1) * ct * pl -
                                (float)(l + m - 1) * plm1) / (float)(l - m);
                    plm1 = pl; pl = pn;
                    int f = l * l + l;
                    if (m == 0) cb[f] = Kc[f] * pl;
                    else {
                        cb[f + m] = Kc[f + m] * cm[m] * pl;
                        cb[f - m] = Kc[f - m] * sm[m] * pl;
                    }
                }
            }
        }
    } else if (tid >= 64 && tid < 64 + 6 * TPB) {
        // rbf: 6 threads per triplet, 7 Bessel evals each (sinf/cosf by value)
        int w = tid - 64;
        int s = w / 6, p = w - 6 * s;
        int t = t0 + s;
        int tc = t < T ? t : T - 1;
        int idx = idx_kj[tc];
        float x = dist[idx] * 0.2f;
        int jlo = p * 7;
        for (int jj = jlo; jj < jlo + 7; ++jj) {
            int l = jj / 6;
            float arg = zc[jj] * x;
            float s1 = sinf(arg), c1 = cosf(arg);
            float inv = 1.0f / arg;
            float j0 = s1 * inv;
            float val = j0;
            if (l >= 1) {
                float jm = j0;
                float jcur = (s1 * inv - c1) * inv;
                for (int ll = 2; ll <= l; ++ll) {
                    float tmp = (float)(2 * ll - 1) * inv * jcur - jm;
                    jm = jcur;
                    jcur = tmp;
                }
                val = jcur;
            }
            rbf_s[s * 44 + jj] = nc[jj] * val;
        }
    }
    __syncthreads();

    int nvalid = T - t0; if (nvalid > TPB) nvalid = TPB;

    if (nvalid == TPB) {
        // ---- phase 2: register products -> flat nontemporal dwordx4 stores.
        // Even col-pair shares a = c/42 and q = a*7 + (c%42)/6 (q never splits a pair).
        f4* __restrict__ gT = (f4*)(outT + (size_t)t0 * TW);
        unsigned row = (unsigned)(4 * tid) / 294u;
        unsigned c   = (unsigned)(4 * tid) - row * 294u;
        #pragma unroll
        for (int it = 0; it < 10; ++it) {
            if (it < 9 || tid < 48) {
                unsigned row1 = row, c1 = c + 2;
                if (c1 >= 294u) { c1 -= 294u; row1 += 1; }
                unsigned a0 = c / 42u,  r0 = c - a0 * 42u,  q0 = a0 * 7u + r0 / 6u;
                unsigned a1 = c1 / 42u, r1 = c1 - a1 * 42u, q1 = a1 * 7u + r1 / 6u;
                float qv0 = cbf_s[row * 49 + q0];
                float2 rv0 = *(const float2*)&rbf_s[row * 44 + r0];
                float qv1 = cbf_s[row1 * 49 + q1];
                float2 rv1 = *(const float2*)&rbf_s[row1 * 44 + r1];
                f4 val = { qv0 * rv0.x, qv0 * rv0.y, qv1 * rv1.x, qv1 * rv1.y };
                __builtin_nontemporal_store(val, gT + it * 256 + tid);
            }
            c += 142u; row += 3u;
            if (c >= 294u) { c -= 294u; row += 1u; }
        }
        f4* __restrict__ gA = (f4*)(outA + (size_t)t0 * 42);
        unsigned arow = (unsigned)(4 * tid) / 42u;
        unsigned ac   = (unsigned)(4 * tid) - arow * 42u;
        #pragma unroll
        for (int it = 0; it < 2; ++it) {
            if (it < 1 || tid < 80) {
                unsigned arow1 = arow, ac1 = ac + 2;
                if (ac1 >= 42u) { ac1 -= 42u; arow1 += 1; }
                unsigned l0 = ac / 6u,  qa0 = l0 * l0 + l0;
                unsigned l1 = ac1 / 6u, qa1 = l1 * l1 + l1;
                float qv0 = cbf_s[arow * 49 + qa0];
                float2 rv0 = *(const float2*)&rbf_s[arow * 44 + ac];
                float qv1 = cbf_s[arow1 * 49 + qa1];
                float2 rv1 = *(const float2*)&rbf_s[arow1 * 44 + ac1];
                f4 val = { qv0 * rv0.x, qv0 * rv0.y, qv1 * rv1.x, qv1 * rv1.y };
                __builtin_nontemporal_store(val, gA + it * 256 + tid);
            }
            ac += 16u; arow += 24u;  // +1024 floats = 24*42 + 16
            if (ac >= 42u) { ac -= 42u; arow += 1u; }
        }
    } else {
        // partial tail block (not hit when T % TPB == 0) — safe scalar path
        for (int g = tid; g < nvalid * TW; g += 256) {
            int row = g / TW, cc = g - row * TW;
            int a = cc / 42, r = cc - a * 42;
            outT[(size_t)t0 * TW + g] = cbf_s[row * 49 + a * 7 + r / 6] * rbf_s[row * 44 + r];
        }
        for (int g = tid; g < nvalid * 42; g += 256) {
            int row = g / 42, r = g - row * 42;
            int l = r / 6;
            outA[(size_t)t0 * 42 + g] = cbf_s[row * 49 + l * l + l] * rbf_s[row * 44 + r];
        }
    }
}

extern "C" void kernel_launch(void* const* d_in, const int* in_sizes, int n_in,
                              void* d_out, int out_size, void* d_ws, size_t ws_size,
                              hipStream_t stream) {
    const float* dist    = (const float*)d_in[0];
    const float* angle   = (const float*)d_in[1];
    const float* torsion = (const float*)d_in[2];
    const float* freq    = (const float*)d_in[3];
    const int*   idx_kj  = (const int*)d_in[4];
    const int E = in_sizes[0];
    const int T = in_sizes[1];
    float* out = (float*)d_out;
    float* outA = out + (size_t)E * NK;
    float* outT = outA + (size_t)T * 42;

    const int NBT = (T + TPB - 1) / TPB;
    const int NBD = (E + 255) / 256;
    fused_kernel<<<NBT + NBD, 256, 0, stream>>>(dist, angle, torsion, freq, idx_kj,
                                                out, outA, outT, E, T, NBT);
}

// Round 10
// 159.011 us; speedup vs baseline: 1.3412x; 1.0081x over previous
//
#include <hip/hip_runtime.h>

#define NS 7
#define NK 6
#define TW 294   // torsion row width = NS*NS*NK
#define TPB 32   // triplets per block

typedef float f4 __attribute__((ext_vector_type(4)));

// Initial guesses for zeros of spherical Bessel j_l, l=1..6, k=1..6.
// Polished on-device by 4 Newton iterations (quadratic convergence; spacing
// between zeros ~pi so guesses accurate to ~1e-3 converge to f32 machine eps).
__constant__ float ZG[6][6] = {
    {4.4934095f, 7.7252518f, 10.9041217f, 14.0661939f, 17.2207553f, 20.3713030f},
    {5.7634592f, 9.0950113f, 12.3229410f, 15.5146030f, 18.6890364f, 21.8538742f},
    {6.9879320f, 10.4171185f, 13.6980232f, 16.9236213f, 20.1218062f, 23.3042470f},
    {8.1825615f, 11.7049072f, 15.0396647f, 18.3012560f, 21.5254177f, 24.7275655f},
    {9.3558121f, 12.9665302f, 16.3547096f, 19.6531521f, 22.9045506f, 26.1277501f},
    {10.5128354f, 14.2073925f, 17.6479743f, 20.9834631f, 24.2627681f, 27.5078684f}
};

// j_{l-1}, j_l at x via upward recurrence. Newton polish path keeps precise
// ocml sinf/cosf (runs once per block, accuracy of zeros matters).
__device__ __forceinline__ void jl_pair(float x, int l, float* jlm1, float* jl) {
    float s = sinf(x), c = cosf(x);
    float inv = 1.0f / x;
    float jm = c * inv;        // j_{-1}
    float j = s * inv;         // j_0
    for (int ll = 1; ll <= l; ++ll) {
        float t = (float)(2 * ll - 1) * inv * j - jm;
        jm = j;
        j = t;
    }
    *jlm1 = jm;
    *jl = j;
}

__launch_bounds__(256, 8)
__global__ void fused_kernel(const float* __restrict__ dist,
                             const float* __restrict__ angle,
                             const float* __restrict__ torsion,
                             const float* __restrict__ freq,
                             const int* __restrict__ idx_kj,
                             float* __restrict__ outD,
                             float* __restrict__ outA,
                             float* __restrict__ outT,
                             int E, int T, int NBT) {
    // shared memory union:
    // triplet path: rbf [32][44] @0, cbf [32][49] @1408, zc @2976, nc @3018, Kc @3060
    // dist path:    buf[1536] @0
    __shared__ __align__(16) float smem[3112];
    const int tid = threadIdx.x;

    if (blockIdx.x >= NBT) {
        // ================= dist-embedding path =================
        const int e0 = (blockIdx.x - NBT) * 256;
        int e = e0 + tid;
        int ec = e < E ? e : E - 1;
        float x = dist[ec] * 0.2f;
        float inv = 1.0f / x;
        float x2 = x * x;
        float xp0 = x2 * x2 * x;  // x^5
        float env = inv - 28.0f * xp0 + 48.0f * xp0 * x - 21.0f * xp0 * x2;
        float v[NK];
        #pragma unroll
        for (int i = 0; i < NK; ++i) v[i] = env * __sinf(freq[i] * x);
        if (e0 + 256 <= E) {
            #pragma unroll
            for (int i = 0; i < NK; ++i) smem[tid * 6 + i] = v[i];
            __syncthreads();
            const f4* b4 = (const f4*)smem;
            f4* o4 = (f4*)(outD + (size_t)e0 * 6);
            __builtin_nontemporal_store(b4[tid], o4 + tid);
            if (tid < 128) __builtin_nontemporal_store(b4[256 + tid], o4 + 256 + tid);
        } else if (e < E) {
            #pragma unroll
            for (int i = 0; i < NK; ++i) outD[(size_t)e * 6 + i] = v[i];
        }
        return;
    }

    // ================= triplet path =================
    float* __restrict__ rbf_s = smem;          // [32][44]
    float* __restrict__ cbf_s = smem + 1408;   // [32][49]
    float* __restrict__ zc    = smem + 2976;   // 42
    float* __restrict__ nc    = smem + 3018;   // 42
    float* __restrict__ Kc    = smem + 3060;   // 49

    // ---- phase 0: per-block constant tables (cheap; hidden under store backpressure)
    if (tid < 42) {
        int l = tid / 6, i = tid - 6 * l;
        if (l == 0) {
            float z = (float)(i + 1) * 3.14159265358979f;
            zc[tid] = z;
            nc[tid] = z * 1.41421356237309f;   // sqrt(2)*k*pi exactly
        } else {
            float x = ZG[l - 1][i];
            #pragma unroll
            for (int it = 0; it < 4; ++it) {   // Newton polish
                float jm, jv;
                jl_pair(x, l, &jm, &jv);
                float d = jm - (float)(l + 1) / x * jv;  // j_l'(x)
                x -= jv / d;
            }
            float jm, jv;
            jl_pair(x, l, &jm, &jv);
            float jn1 = (float)(2 * l + 1) / x * jv - jm;  // j_{l+1}(x)
            zc[tid] = x;
            nc[tid] = 1.41421356237309f / fabsf(jn1);
        }
    } else if (tid >= 64 && tid < 113) {
        int f = tid - 64;
        int l = 0;
        while ((l + 1) * (l + 1) <= f) ++l;
        int m = f - l * l - l;
        int am = m < 0 ? -m : m;
        float ratio = 1.0f;
        for (int t = l - am + 1; t <= l + am; ++t) ratio /= (float)t;
        float K = sqrtf((float)(2 * l + 1) * 0.07957747154594767f * ratio);
        if (m != 0) K *= 1.41421356237309505f;
        Kc[f] = K;
    }
    const int t0 = blockIdx.x * TPB;
    __syncthreads();

    // ---- phase 1
    if (tid < TPB) {
        // cbf[49] for triplet slot `tid`, m-major (3-deep P chain)
        int t = t0 + tid;
        int tc = t < T ? t : T - 1;
        float ang = angle[tc];
        float phi = torsion[tc];

        float st = __sinf(ang), ct = __cosf(ang);
        float sp = __sinf(phi), cp = __cosf(phi);
        float sm[NS], cm[NS];
        sm[1] = sp; cm[1] = cp;
        #pragma unroll
        for (int m = 2; m < NS; ++m) {
            sm[m] = sm[m - 1] * cp + cm[m - 1] * sp;
            cm[m] = cm[m - 1] * cp - sm[m - 1] * sp;
        }

        float* cb = cbf_s + tid * 49;
        float pmm = 1.0f;  // P[m][m]
        #pragma unroll
        for (int m = 0; m < NS; ++m) {
            if (m > 0) pmm = (float)(1 - 2 * m) * pmm * st;
            {
                int f = m * m + m;
                if (m == 0) cb[f] = Kc[f];
                else {
                    cb[f + m] = Kc[f + m] * cm[m] * pmm;
                    cb[f - m] = Kc[f - m] * sm[m] * pmm;
                }
            }
            if (m < NS - 1) {
                float plm1 = pmm;
                float pl = (float)(2 * m + 1) * ct * pmm;  // P[m+1][m]
                {
                    int l = m + 1, f = l * l + l;
                    if (m == 0) cb[f] = Kc[f] * pl;
                    else {
                        cb[f + m] = Kc[f + m] * cm[m] * pl;
                        cb[f - m] = Kc[f - m] * sm[m] * pl;
                    }
                }
                #pragma unroll
                for (int l = m + 2; l < NS; ++l) {
                    float pn = ((float)(2 * l - 1) * ct * pl -
                                (float)(l + m - 1) * plm1) / (float)(l - m);
                    plm1 = pl; pl = pn;
                    int f = l * l + l;
                    if (m == 0) cb[f] = Kc[f] * pl;
                    else {
                        cb[f + m] = Kc[f + m] * cm[m] * pl;
                        cb[f - m] = Kc[f - m] * sm[m] * pl;
                    }
                }
            }
        }
    } else if (tid >= 64 && tid < 64 + 6 * TPB) {
        // rbf: 6 threads per triplet, 7 Bessel evals each (v_sin/v_cos fast trig)
        int w = tid - 64;
        int s = w / 6, p = w - 6 * s;
        int t = t0 + s;
        int tc = t < T ? t : T - 1;
        int idx = idx_kj[tc];
        float x = dist[idx] * 0.2f;
        int jlo = p * 7;
        for (int jj = jlo; jj < jlo + 7; ++jj) {
            int l = jj / 6;
            float arg = zc[jj] * x;
            float s1 = __sinf(arg), c1 = __cosf(arg);
            float inv = 1.0f / arg;
            float j0 = s1 * inv;
            float val = j0;
            if (l >= 1) {
                float jm = j0;
                float jcur = (s1 * inv - c1) * inv;
                for (int ll = 2; ll <= l; ++ll) {
                    float tmp = (float)(2 * ll - 1) * inv * jcur - jm;
                    jm = jcur;
                    jcur = tmp;
                }
                val = jcur;
            }
            rbf_s[s * 44 + jj] = nc[jj] * val;
        }
    }
    __syncthreads();

    int nvalid = T - t0; if (nvalid > TPB) nvalid = TPB;

    if (nvalid == TPB) {
        // ---- phase 2: register products -> flat nontemporal dwordx4 stores.
        // Even col-pair shares a = c/42 and q = a*7 + (c%42)/6 (q never splits a pair).
        f4* __restrict__ gT = (f4*)(outT + (size_t)t0 * TW);
        unsigned row = (unsigned)(4 * tid) / 294u;
        unsigned c   = (unsigned)(4 * tid) - row * 294u;
        #pragma unroll
        for (int it = 0; it < 10; ++it) {
            if (it < 9 || tid < 48) {
                unsigned row1 = row, c1 = c + 2;
                if (c1 >= 294u) { c1 -= 294u; row1 += 1; }
                unsigned a0 = c / 42u,  r0 = c - a0 * 42u,  q0 = a0 * 7u + r0 / 6u;
                unsigned a1 = c1 / 42u, r1 = c1 - a1 * 42u, q1 = a1 * 7u + r1 / 6u;
                float qv0 = cbf_s[row * 49 + q0];
                float2 rv0 = *(const float2*)&rbf_s[row * 44 + r0];
                float qv1 = cbf_s[row1 * 49 + q1];
                float2 rv1 = *(const float2*)&rbf_s[row1 * 44 + r1];
                f4 val = { qv0 * rv0.x, qv0 * rv0.y, qv1 * rv1.x, qv1 * rv1.y };
                __builtin_nontemporal_store(val, gT + it * 256 + tid);
            }
            c += 142u; row += 3u;
            if (c >= 294u) { c -= 294u; row += 1u; }
        }
        f4* __restrict__ gA = (f4*)(outA + (size_t)t0 * 42);
        unsigned arow = (unsigned)(4 * tid) / 42u;
        unsigned ac   = (unsigned)(4 * tid) - arow * 42u;
        #pragma unroll
        for (int it = 0; it < 2; ++it) {
            if (it < 1 || tid < 80) {
                unsigned arow1 = arow, ac1 = ac + 2;
                if (ac1 >= 42u) { ac1 -= 42u; arow1 += 1; }
                unsigned l0 = ac / 6u,  qa0 = l0 * l0 + l0;
                unsigned l1 = ac1 / 6u, qa1 = l1 * l1 + l1;
                float qv0 = cbf_s[arow * 49 + qa0];
                float2 rv0 = *(const float2*)&rbf_s[arow * 44 + ac];
                float qv1 = cbf_s[arow1 * 49 + qa1];
                float2 rv1 = *(const float2*)&rbf_s[arow1 * 44 + ac1];
                f4 val = { qv0 * rv0.x, qv0 * rv0.y, qv1 * rv1.x, qv1 * rv1.y };
                __builtin_nontemporal_store(val, gA + it * 256 + tid);
            }
            ac += 16u; arow += 24u;  // +1024 floats = 24*42 + 16
            if (ac >= 42u) { ac -= 42u; arow += 1u; }
        }
    } else {
        // partial tail block (not hit when T % TPB == 0) — safe scalar path
        for (int g = tid; g < nvalid * TW; g += 256) {
            int row = g / TW, cc = g - row * TW;
            int a = cc / 42, r = cc - a * 42;
            outT[(size_t)t0 * TW + g] = cbf_s[row * 49 + a * 7 + r / 6] * rbf_s[row * 44 + r];
        }
        for (int g = tid; g < nvalid * 42; g += 256) {
            int row = g / 42, r = g - row * 42;
            int l = r / 6;
            outA[(size_t)t0 * 42 + g] = cbf_s[row * 49 + l * l + l] * rbf_s[row * 44 + r];
        }
    }
}

extern "C" void kernel_launch(void* const* d_in, const int* in_sizes, int n_in,
                              void* d_out, int out_size, void* d_ws, size_t ws_size,
                              hipStream_t stream) {
    const float* dist    = (const float*)d_in[0];
    const float* angle   = (const float*)d_in[1];
    const float* torsion = (const float*)d_in[2];
    const float* freq    = (const float*)d_in[3];
    const int*   idx_kj  = (const int*)d_in[4];
    const int E = in_sizes[0];
    const int T = in_sizes[1];
    float* out = (float*)d_out;
    float* outA = out + (size_t)E * NK;
    float* outT = outA + (size_t)T * 42;

    const int NBT = (T + TPB - 1) / TPB;
    const int NBD = (E + 255) / 256;
    fused_kernel<<<NBT + NBD, 256, 0, stream>>>(dist, angle, torsion, freq, idx_kj,
                                                out, outA, outT, E, T, NBT);
}